// Round 1
// baseline (4734.195 us; speedup 1.0000x reference)
//
#include <hip/hip_runtime.h>
#include <stdint.h>

#define BATCH 8
#define NPTS 4096
#define KNN 20
#define HDIM 64
constexpr float SLOPE = 0.2f;

// ---------------------------------------------------------------------------
// Kernel 1: per-point u = X @ W1b, c = X @ W1a - u + b1, plus squared norms.
//   Factorization: h1(i,j) = lrelu([x_i | x_j-x_i] @ W1 + b1) = lrelu(c_i + u_j)
//   with W1a = W1[0:D], W1b = W1[D:2D].
// ---------------------------------------------------------------------------
template<int D>
__global__ __launch_bounds__(256) void uc_kernel(
    const float* __restrict__ X,    // [B*N][D]
    const float* __restrict__ W1,   // [2D][64]
    const float* __restrict__ b1,   // [64]
    float* __restrict__ u,          // [B*N][64]
    float* __restrict__ cvec,       // [B*N][64]
    float* __restrict__ sqv)        // [B*N]
{
    __shared__ float Xs[16 * D];
    const int n0 = blockIdx.x * 16;
    const int t  = threadIdx.x;
    for (int i = t; i < 16 * D; i += 256)
        Xs[i] = X[(size_t)n0 * D + i];
    __syncthreads();

    if (t < 16) {
        float s = 0.f;
        #pragma unroll
        for (int d = 0; d < D; ++d) { float v = Xs[t * D + d]; s += v * v; }
        sqv[n0 + t] = s;
    }

    const int o  = t & 63;
    const int pg = t >> 6;      // handles points pg*4 .. pg*4+3
    float va[4] = {0.f, 0.f, 0.f, 0.f};
    float vb[4] = {0.f, 0.f, 0.f, 0.f};
    for (int d = 0; d < D; ++d) {
        const float wa = W1[d * 64 + o];
        const float wb = W1[(D + d) * 64 + o];
        #pragma unroll
        for (int pi = 0; pi < 4; ++pi) {
            const float x = Xs[(pg * 4 + pi) * D + d];
            va[pi] += x * wa;
            vb[pi] += x * wb;
        }
    }
    const float bo = b1[o];
    #pragma unroll
    for (int pi = 0; pi < 4; ++pi) {
        const size_t n = (size_t)n0 + pg * 4 + pi;
        u[n * 64 + o]    = vb[pi];
        cvec[n * 64 + o] = va[pi] - vb[pi] + bo;
    }
}

// ---------------------------------------------------------------------------
// Kernel 2: kNN (K=20 smallest d = |xi|^2+|xj|^2-2 xi.xj, tie-break low index).
// Block: 256 thr, 64 queries, loop 64 candidate tiles of 64.
// Phase A: 4x4 register micro-tile distance GEMM (float4 LDS reads; candidate
//          tile chunk-XOR-swizzled to avoid 8-way bank conflicts).
// Phase B: per-thread register top-20 over a 16-column slice (u64 keys:
//          monotone float bits << 32 | j  -> min == nearest, ties -> low j).
// Merge:   4 sorted lists per query -> 20 smallest.
// ---------------------------------------------------------------------------
__device__ __forceinline__ unsigned long long pack_key(float d, int j) {
    unsigned ub = __float_as_uint(d);
    ub = (ub & 0x80000000u) ? ~ub : (ub | 0x80000000u);
    return ((unsigned long long)ub << 32) | (unsigned)j;
}

template<int D4>   // D4=1 -> D=3 (pos), D4=16 -> D=64
__global__ __launch_bounds__(256) void knn_kernel(
    const float* __restrict__ X,
    const float* __restrict__ sq,
    int* __restrict__ knn_idx)       // [B*N][20]
{
    constexpr int D    = (D4 == 1) ? 3 : D4 * 4;
    constexpr int STR  = D4 * 4 + 4;
    constexpr int XQ_F = 64 * STR;
    constexpr int BASE = 2 * XQ_F + 128 + 64 * 68;
    constexpr int SMEMF = (BASE > 10240) ? BASE : 10240;   // lists alias needs 40960 B
    __shared__ alignas(16) float smem[SMEMF];
    float* xq   = smem;
    float* xj   = smem + XQ_F;          // D4==1: stores transposed [3][68]
    float* sqq  = smem + 2 * XQ_F;
    float* sqj  = sqq + 64;
    float* dist = sqj + 64;             // [64][68]
    unsigned long long* lists = (unsigned long long*)smem;  // alias (after final sync)

    const int t     = threadIdx.x;
    const int b     = blockIdx.y;
    const int qbase = blockIdx.x * 64;
    const float* Xb  = X  + (size_t)b * NPTS * D;
    const float* sqb = sq + (size_t)b * NPTS;

    // stage query tile
    if constexpr (D4 == 1) {
        if (t < 64) {
            const float* row = Xb + (size_t)(qbase + t) * 3;
            xq[t * STR + 0] = row[0]; xq[t * STR + 1] = row[1];
            xq[t * STR + 2] = row[2]; xq[t * STR + 3] = 0.f;
            sqq[t] = sqb[qbase + t];
        }
    } else {
        for (int ci = t; ci < 64 * D4; ci += 256) {
            const int r = ci >> 4, c4 = ci & 15;
            *(float4*)&xq[r * STR + 4 * c4] =
                *(const float4*)&Xb[(size_t)(qbase + r) * D + 4 * c4];
        }
        if (t < 64) sqq[t] = sqb[qbase + t];
    }
    __syncthreads();

    const int qg = t >> 4, jg = t & 15;   // phase A mapping
    const int q  = t >> 2, s  = t & 3;    // phase B mapping

    float sqq_r[4];
    #pragma unroll
    for (int rr = 0; rr < 4; ++rr) sqq_r[rr] = sqq[4 * qg + rr];
    float4 aq[4];
    if constexpr (D4 == 1) {
        #pragma unroll
        for (int rr = 0; rr < 4; ++rr)
            aq[rr] = *(const float4*)&xq[(4 * qg + rr) * STR];
    }

    unsigned long long lst[KNN];
    #pragma unroll
    for (int k = 0; k < KNN; ++k) lst[k] = ~0ULL;

    for (int jt = 0; jt < 64; ++jt) {
        const int jbase = jt * 64;
        // stage candidate tile
        if constexpr (D4 == 1) {
            if (t < 64) {
                const float* row = Xb + (size_t)(jbase + t) * 3;
                xj[0 * 68 + t] = row[0];
                xj[1 * 68 + t] = row[1];
                xj[2 * 68 + t] = row[2];
                sqj[t] = sqb[jbase + t];
            }
        } else {
            for (int ci = t; ci < 64 * D4; ci += 256) {
                const int r = ci >> 4, c4 = ci & 15;
                const int c4s = c4 ^ ((r >> 2) & 3);      // chunk swizzle
                *(float4*)&xj[r * STR + 4 * c4s] =
                    *(const float4*)&Xb[(size_t)(jbase + r) * D + 4 * c4];
            }
            if (t < 64) sqj[t] = sqb[jbase + t];
        }
        __syncthreads();

        // ---- phase A: distances into dist[64][68]
        if constexpr (D4 == 1) {
            #pragma unroll
            for (int cc = 0; cc < 4; ++cc) {
                const int jr = 4 * jg + cc;
                const float jx = xj[0 * 68 + jr], jy = xj[1 * 68 + jr], jz = xj[2 * 68 + jr];
                const float sj = sqj[jr];
                #pragma unroll
                for (int rr = 0; rr < 4; ++rr) {
                    const float dot = aq[rr].x * jx + aq[rr].y * jy + aq[rr].z * jz;
                    dist[(4 * qg + rr) * 68 + jr] = sqq_r[rr] + sj - 2.f * dot;
                }
            }
        } else {
            float acc[4][4];
            #pragma unroll
            for (int rr = 0; rr < 4; ++rr)
                #pragma unroll
                for (int cc = 0; cc < 4; ++cc) acc[rr][cc] = 0.f;
            #pragma unroll
            for (int k = 0; k < D4; ++k) {
                float4 a[4], bv[4];
                #pragma unroll
                for (int rr = 0; rr < 4; ++rr)
                    a[rr] = *(const float4*)&xq[(4 * qg + rr) * STR + 4 * k];
                const int kx = k ^ (jg & 3);
                #pragma unroll
                for (int cc = 0; cc < 4; ++cc)
                    bv[cc] = *(const float4*)&xj[(4 * jg + cc) * STR + 4 * kx];
                #pragma unroll
                for (int rr = 0; rr < 4; ++rr)
                    #pragma unroll
                    for (int cc = 0; cc < 4; ++cc)
                        acc[rr][cc] += a[rr].x * bv[cc].x + a[rr].y * bv[cc].y
                                     + a[rr].z * bv[cc].z + a[rr].w * bv[cc].w;
            }
            #pragma unroll
            for (int rr = 0; rr < 4; ++rr)
                #pragma unroll
                for (int cc = 0; cc < 4; ++cc)
                    dist[(4 * qg + rr) * 68 + 4 * jg + cc] =
                        sqq_r[rr] + sqj[4 * jg + cc] - 2.f * acc[rr][cc];
        }
        __syncthreads();

        // ---- phase B: update per-thread top-20 over 16 columns of row q
        for (int i = 0; i < 16; ++i) {
            const int col = s * 16 + i;
            const float d = dist[q * 68 + col];
            const unsigned long long key = pack_key(d, jbase + col);
            if (key < lst[KNN - 1]) {
                unsigned long long c = key;
                #pragma unroll
                for (int k = 0; k < KNN; ++k) {
                    const unsigned long long lo = (lst[k] < c) ? lst[k] : c;
                    const unsigned long long hi = (lst[k] < c) ? c : lst[k];
                    lst[k] = lo; c = hi;
                }
            }
        }
    }
    __syncthreads();   // everyone done with dist before aliasing

    #pragma unroll
    for (int k = 0; k < KNN; ++k) lists[t * KNN + k] = lst[k];
    __syncthreads();

    if (t < 64) {
        const unsigned long long* L0 = lists + (size_t)(t * 4 + 0) * KNN;
        const unsigned long long* L1 = L0 + KNN;
        const unsigned long long* L2 = L1 + KNN;
        const unsigned long long* L3 = L2 + KNN;
        int p0 = 0, p1 = 0, p2 = 0, p3 = 0;
        int* outp = knn_idx + ((size_t)b * NPTS + qbase + t) * KNN;
        for (int k = 0; k < KNN; ++k) {
            const unsigned long long h0 = L0[p0], h1 = L1[p1], h2 = L2[p2], h3 = L3[p3];
            const unsigned long long m01 = (h0 < h1) ? h0 : h1;
            const unsigned long long m23 = (h2 < h3) ? h2 : h3;
            const unsigned long long m   = (m01 < m23) ? m01 : m23;
            outp[k] = (int)(unsigned)(m & 0xffffffffu);
            if (m == h0) ++p0; else if (m == h1) ++p1; else if (m == h2) ++p2; else ++p3;
        }
    }
}

// ---------------------------------------------------------------------------
// Kernel 3: fused edge MLP + max aggregation.
// 4 points (80 edges) per block. h1 = lrelu(c_i + u_j) formed in LDS,
// then two 80x64x64 GEMMs (5x4 register micro-tile, float4 LDS reads,
// weights staged per-phase) with lrelu, then max over the 20 edges.
// ---------------------------------------------------------------------------
template<bool FINAL>
__device__ __forceinline__ void block_gemm_lrelu(
    const float* __restrict__ Xs,   // [80][68]
    const float* __restrict__ Ws,   // [64][64]
    const float* __restrict__ bias, // global [64]
    float* __restrict__ Ys,         // [80][68] (if !FINAL)
    float* __restrict__ mxs,        // [16][64] (if FINAL)
    const int t)
{
    const int rg = t >> 4, og = t & 15;
    float acc[5][4];
    #pragma unroll
    for (int oc = 0; oc < 4; ++oc) {
        const float bb = bias[4 * og + oc];
        #pragma unroll
        for (int rr = 0; rr < 5; ++rr) acc[rr][oc] = bb;
    }
    #pragma unroll
    for (int k4 = 0; k4 < 16; ++k4) {
        float4 xv[5];
        #pragma unroll
        for (int rr = 0; rr < 5; ++rr)
            xv[rr] = *(const float4*)&Xs[(5 * rg + rr) * 68 + 4 * k4];
        float4 wv[4];
        #pragma unroll
        for (int kk = 0; kk < 4; ++kk)
            wv[kk] = *(const float4*)&Ws[(4 * k4 + kk) * 64 + 4 * og];
        #pragma unroll
        for (int rr = 0; rr < 5; ++rr) {
            acc[rr][0] += xv[rr].x * wv[0].x + xv[rr].y * wv[1].x + xv[rr].z * wv[2].x + xv[rr].w * wv[3].x;
            acc[rr][1] += xv[rr].x * wv[0].y + xv[rr].y * wv[1].y + xv[rr].z * wv[2].y + xv[rr].w * wv[3].y;
            acc[rr][2] += xv[rr].x * wv[0].z + xv[rr].y * wv[1].z + xv[rr].z * wv[2].z + xv[rr].w * wv[3].z;
            acc[rr][3] += xv[rr].x * wv[0].w + xv[rr].y * wv[1].w + xv[rr].z * wv[2].w + xv[rr].w * wv[3].w;
        }
    }
    if constexpr (!FINAL) {
        #pragma unroll
        for (int rr = 0; rr < 5; ++rr)
            #pragma unroll
            for (int oc = 0; oc < 4; ++oc) {
                float v = acc[rr][oc];
                v = (v > 0.f) ? v : SLOPE * v;
                Ys[(5 * rg + rr) * 68 + 4 * og + oc] = v;
            }
    } else {
        // thread's 5 rows lie within one point (20 % 5 == 0)
        #pragma unroll
        for (int oc = 0; oc < 4; ++oc) {
            float m = -1e30f;
            #pragma unroll
            for (int rr = 0; rr < 5; ++rr) {
                float v = acc[rr][oc];
                v = (v > 0.f) ? v : SLOPE * v;
                m = fmaxf(m, v);
            }
            mxs[rg * 64 + 4 * og + oc] = m;
        }
    }
}

__global__ __launch_bounds__(256) void edge_kernel(
    const float* __restrict__ u,
    const float* __restrict__ cvec,
    const int* __restrict__ knn_idx,
    const float* __restrict__ W2, const float* __restrict__ b2,
    const float* __restrict__ W3, const float* __restrict__ b3,
    float* __restrict__ out)        // [B*N][64]
{
    __shared__ alignas(16) float h1s[80 * 68];
    __shared__ alignas(16) float h2s[80 * 68];
    __shared__ alignas(16) float Ws[64 * 64];
    __shared__ float cs[256];
    __shared__ float mxs[16 * 64];
    __shared__ int   idxs[80];

    const int t  = threadIdx.x;
    const int p0 = blockIdx.x * 4;      // 4 points per block
    const int b  = p0 >> 12;

    cs[t] = cvec[(size_t)p0 * 64 + t];
    if (t < 80) idxs[t] = knn_idx[(size_t)p0 * KNN + t];
    for (int i = t; i < 4096; i += 256) Ws[i] = W2[i];
    __syncthreads();

    {   // h1 formation: h1 = lrelu(c_i + u_j)
        const int wave = t >> 6, lane = t & 63;
        for (int e = wave; e < 80; e += 4) {
            const int j = idxs[e];
            const float val = u[((size_t)(b << 12) + j) * 64 + lane];
            const float pre = cs[(e / 20) * 64 + lane] + val;
            h1s[e * 68 + lane] = (pre > 0.f) ? pre : SLOPE * pre;
        }
    }
    __syncthreads();

    block_gemm_lrelu<false>(h1s, Ws, b2, h2s, nullptr, t);
    __syncthreads();

    for (int i = t; i < 4096; i += 256) Ws[i] = W3[i];
    __syncthreads();

    block_gemm_lrelu<true>(h2s, Ws, b3, nullptr, mxs, t);
    __syncthreads();

    const int p = t >> 6, col = t & 63;
    const float m = fmaxf(fmaxf(mxs[(4 * p + 0) * 64 + col], mxs[(4 * p + 1) * 64 + col]),
                          fmaxf(mxs[(4 * p + 2) * 64 + col], mxs[(4 * p + 3) * 64 + col]));
    out[(size_t)(p0 + p) * 64 + col] = m;
}

// ---------------------------------------------------------------------------
extern "C" void kernel_launch(void* const* d_in, const int* in_sizes, int n_in,
                              void* d_out, int out_size, void* d_ws, size_t ws_size,
                              hipStream_t stream) {
    const float* pos = (const float*)d_in[0];
    const float* w11 = (const float*)d_in[1];  const float* b11 = (const float*)d_in[2];
    const float* w12 = (const float*)d_in[3];  const float* b12 = (const float*)d_in[4];
    const float* w13 = (const float*)d_in[5];  const float* b13 = (const float*)d_in[6];
    const float* w21 = (const float*)d_in[7];  const float* b21 = (const float*)d_in[8];
    const float* w22 = (const float*)d_in[9];  const float* b22 = (const float*)d_in[10];
    const float* w23 = (const float*)d_in[11]; const float* b23 = (const float*)d_in[12];
    const float* w31 = (const float*)d_in[13]; const float* b31 = (const float*)d_in[14];
    const float* w32 = (const float*)d_in[15]; const float* b32 = (const float*)d_in[16];
    const float* w33 = (const float*)d_in[17]; const float* b33 = (const float*)d_in[18];

    const int BN = BATCH * NPTS;   // 32768
    float* ws = (float*)d_ws;
    float* x1   = ws;                  // [BN][64]
    float* x2   = x1 + (size_t)BN * 64;
    float* ubuf = x2 + (size_t)BN * 64;
    float* cbuf = ubuf + (size_t)BN * 64;
    float* sqb  = cbuf + (size_t)BN * 64;
    int*   idx  = (int*)(sqb + BN);    // [BN][20]

    const dim3 knn_grid(NPTS / 64, BATCH);

    // EdgeConv 1 (D=3)
    uc_kernel<3><<<BN / 16, 256, 0, stream>>>(pos, w11, b11, ubuf, cbuf, sqb);
    knn_kernel<1><<<knn_grid, 256, 0, stream>>>(pos, sqb, idx);
    edge_kernel<<<BN / 4, 256, 0, stream>>>(ubuf, cbuf, idx, w12, b12, w13, b13, x1);

    // EdgeConv 2 (D=64)
    uc_kernel<64><<<BN / 16, 256, 0, stream>>>(x1, w21, b21, ubuf, cbuf, sqb);
    knn_kernel<16><<<knn_grid, 256, 0, stream>>>(x1, sqb, idx);
    edge_kernel<<<BN / 4, 256, 0, stream>>>(ubuf, cbuf, idx, w22, b22, w23, b23, x2);

    // EdgeConv 3 (D=64)
    uc_kernel<64><<<BN / 16, 256, 0, stream>>>(x2, w31, b31, ubuf, cbuf, sqb);
    knn_kernel<16><<<knn_grid, 256, 0, stream>>>(x2, sqb, idx);
    edge_kernel<<<BN / 4, 256, 0, stream>>>(ubuf, cbuf, idx, w32, b32, w33, b33, (float*)d_out);
}